// Round 16
// baseline (163.071 us; speedup 1.0000x reference)
//
#include <hip/hip_runtime.h>
#include <math.h>

#define N_NODES 50000
#define D 128
#define MIN_NORM 1e-15f
#define EPS 1e-5f
#define NBUCK 196        // ceil(N_NODES / 256)
#define CHUNK 4096       // edges per block in binA
#define CAP 10240        // bucket capacity (mean 8163 + 8-pad mean ~900 + margin)
#define FSCALE 32.0f     // fp8 storage pre-scale (cancels through linear SpMM)
#define INV_FSCALE (1.0f / 32.0f)

typedef float fx2 __attribute__((ext_vector_type(2)));

// ---------------------------------------------------------------------------
__global__ void zerog_kernel(int* __restrict__ gcur) {
    if (threadIdx.x < NBUCK) gcur[threadIdx.x] = 0;
}

// ---------------------------------------------------------------------------
// binA: count + scatter into CAP-strided bucket regions of tmp.
// Payload packs (rowlocal<<16)|col in .x, f32 val bits in .y.
// ---------------------------------------------------------------------------
__global__ __launch_bounds__(256) void binA_kernel(const int* __restrict__ rows,
                                                   const int* __restrict__ cols,
                                                   const float* __restrict__ vals,
                                                   int* __restrict__ gcur,
                                                   int2* __restrict__ tmp, int E) {
    __shared__ int lh[NBUCK];
    __shared__ int lb[NBUCK];
    for (int i = threadIdx.x; i < NBUCK; i += 256) lh[i] = 0;
    __syncthreads();
    int start = blockIdx.x * CHUNK;
    int end = min(start + CHUNK, E);
    for (int i = start + threadIdx.x; i < end; i += 256)
        atomicAdd(&lh[rows[i] >> 8], 1);
    __syncthreads();
    for (int i = threadIdx.x; i < NBUCK; i += 256) {
        int c = lh[i];
        lb[i] = i * CAP + (c ? atomicAdd(&gcur[i], c) : 0);
        lh[i] = 0;
    }
    __syncthreads();
    for (int i = start + threadIdx.x; i < end; i += 256) {
        int r = rows[i];
        int b = r >> 8;
        int ofs = atomicAdd(&lh[b], 1);
        tmp[lb[b] + ofs] = make_int2(((r & 255) << 16) | cols[i], __float_as_int(vals[i]));
    }
}

// ---------------------------------------------------------------------------
// binB: one block per bucket. Sort bucket edges by local row via 256-entry
// LDS histogram + scan over counts ROUNDED UP TO MULTIPLES OF 8; emit
// rowptr2 = (startEdge, endEdge=start+rounded) and row-sorted epay
// uint2{ col<<7 (byte offset into h), f32 val bits }. Rows padded to a
// multiple of 8 edges with (col=0, val=0) so the SpMM loop is tail-free.
// ---------------------------------------------------------------------------
__global__ __launch_bounds__(256) void binB_kernel(const int2* __restrict__ tmp,
                                                   const int* __restrict__ gcur,
                                                   int2* __restrict__ rowptr2,
                                                   uint2* __restrict__ epay) {
    __shared__ int hist[256];
    __shared__ int wsum[4];
    int b = blockIdx.x;
    int base = b * CAP;
    int nloc = gcur[b];
    int tid = threadIdx.x;
    hist[tid] = 0;
    __syncthreads();
    for (int i = tid; i < nloc; i += 256)
        atomicAdd(&hist[tmp[base + i].x >> 16], 1);
    __syncthreads();
    int lane = tid & 63, wid = tid >> 6;
    int v = hist[tid];
    int r = (v + 7) & ~7;            // 8-rounded count
    int x = r;
    #pragma unroll
    for (int off = 1; off < 64; off <<= 1) {
        int t = __shfl_up(x, off, 64);
        if (lane >= off) x += t;
    }
    if (lane == 63) wsum[wid] = x;
    __syncthreads();
    if (tid == 0) {
        int s0 = wsum[0], s1 = wsum[1], s2 = wsum[2];
        wsum[0] = 0; wsum[1] = s0; wsum[2] = s0 + s1; wsum[3] = s0 + s1 + s2;
    }
    __syncthreads();
    int excl = x - r + wsum[wid];    // 8-aligned start within bucket
    int g = (b << 8) + tid;
    if (g < N_NODES) rowptr2[g] = make_int2(base + excl, base + excl + r);
    __syncthreads();
    hist[tid] = excl;                // per-row scatter cursor
    __syncthreads();
    for (int i = tid; i < nloc; i += 256) {
        int2 p = tmp[base + i];
        int rl = p.x >> 16;
        unsigned col = (unsigned)(p.x & 0xffff);
        int pos = base + atomicAdd(&hist[rl], 1);
        epay[pos] = make_uint2(col << 7, (unsigned)p.y);
    }
    // pad each row to its 8-rounded length (col 0, val 0)
    for (int k = v; k < r; ++k)
        epay[base + excl + k] = make_uint2(0u, 0u);
}

// ---------------------------------------------------------------------------
// h = FSCALE * logmap0(x) -> fp8 e4m3. 4 waves/block, one wave per row;
// lane owns cols {2l, 2l+1}; packed fp8 pair stored as ushort.
// ---------------------------------------------------------------------------
__global__ __launch_bounds__(256) void logmap0_kernel(const float* __restrict__ x,
                                                      unsigned short* __restrict__ h) {
    int lane = threadIdx.x & 63;
    int row = blockIdx.x * 4 + (threadIdx.x >> 6);
    const float2* xr = reinterpret_cast<const float2*>(x + (size_t)row * D);
    float2 v = xr[lane];
    float x0 = __shfl(v.x, 0, 64);
    float sq = v.y * v.y + (lane == 0 ? 0.0f : v.x * v.x);
    #pragma unroll
    for (int off = 1; off < 64; off <<= 1) sq += __shfl_xor(sq, off, 64);
    float ynorm = fmaxf(sqrtf(sq), MIN_NORM);
    float theta = fmaxf(x0, 1.0f + EPS);
    float scale = FSCALE * acoshf(theta) / ynorm;
    float ox = (lane == 0) ? 0.0f : v.x * scale;
    float oy = v.y * scale;
    int packed = __builtin_amdgcn_cvt_pk_fp8_f32(ox, oy, 0, false);
    h[(size_t)row * (D / 2) + lane] = (unsigned short)packed;
}

// ---------------------------------------------------------------------------
// Scalar-pipe CSR SpMM, TWO rows per wave, 16 edges per row per iteration
// (32 gathers in flight per wave). Rows 8-padded -> no scalar tails.
// Per edge the VALU does {ushort gather, cvt_pk_f32_fp8, v_pk_fma_f32}.
// Lane owns cols {2l, 2l+1} (fx2 accumulator -> packed FMA).
// MID: store fp8 (keeps FSCALE). FINAL: fused out = proj(expmap0(acc/FSCALE)).
// ---------------------------------------------------------------------------
template <bool FINAL>
__global__ __launch_bounds__(256) void spmm_kernel(const int4* __restrict__ rowptr4,
                                                   const uint2* __restrict__ epay,
                                                   const unsigned short* __restrict__ hin,
                                                   void* __restrict__ hout) {
    int lane = threadIdx.x & 63;
    int pr = __builtin_amdgcn_readfirstlane(blockIdx.x * 4 + (threadIdx.x >> 6));
    int rA = pr * 2, rB = rA + 1;
    int4 rp = rowptr4[pr];                     // (startA, endA, startB, endB)
    int ja = __builtin_amdgcn_readfirstlane(rp.x), ea = __builtin_amdgcn_readfirstlane(rp.y);
    int jb = __builtin_amdgcn_readfirstlane(rp.z), eb = __builtin_amdgcn_readfirstlane(rp.w);
    const char* hb = (const char*)hin;
    int lo = lane << 1;
    fx2 accA0 = {0.f, 0.f}, accA1 = {0.f, 0.f};   // row A (2 sub-chains)
    fx2 accB0 = {0.f, 0.f}, accB1 = {0.f, 0.f};   // row B (2 sub-chains)
#define EDGE(E, ACC) {                                                        \
    unsigned short g8 = *(const unsigned short*)(hb + (E).x + lo);            \
    fx2 f = __builtin_amdgcn_cvt_pk_f32_fp8((int)g8, false);                  \
    float vs = __uint_as_float((E).y);                                        \
    fx2 vv = {vs, vs};                                                        \
    ACC += f * vv; }
    // main: both rows have >=16 edges left -> 32 gathers in flight
    while (ja + 16 <= ea && jb + 16 <= eb) {
        uint2 xx[16], yy[16];
        #pragma unroll
        for (int i = 0; i < 16; ++i) { xx[i] = epay[ja + i]; yy[i] = epay[jb + i]; }
        #pragma unroll
        for (int i = 0; i < 16; ++i) {
            if (i & 1) { EDGE(xx[i], accA1) EDGE(yy[i], accB1) }
            else       { EDGE(xx[i], accA0) EDGE(yy[i], accB0) }
        }
        ja += 16; jb += 16;
    }
    // both rows have >=8
    while (ja + 8 <= ea && jb + 8 <= eb) {
        uint2 xx[8], yy[8];
        #pragma unroll
        for (int i = 0; i < 8; ++i) { xx[i] = epay[ja + i]; yy[i] = epay[jb + i]; }
        #pragma unroll
        for (int i = 0; i < 8; ++i) {
            if (i & 1) { EDGE(xx[i], accA1) EDGE(yy[i], accB1) }
            else       { EDGE(xx[i], accA0) EDGE(yy[i], accB0) }
        }
        ja += 8; jb += 8;
    }
    // per-row remainders (multiples of 8, 16 gathers in flight)
    for (; ja + 8 <= ea; ja += 8) {
        uint2 xx[8];
        #pragma unroll
        for (int i = 0; i < 8; ++i) xx[i] = epay[ja + i];
        #pragma unroll
        for (int i = 0; i < 8; ++i) {
            if (i & 1) { EDGE(xx[i], accA1) }
            else       { EDGE(xx[i], accA0) }
        }
    }
    for (; jb + 8 <= eb; jb += 8) {
        uint2 yy[8];
        #pragma unroll
        for (int i = 0; i < 8; ++i) yy[i] = epay[jb + i];
        #pragma unroll
        for (int i = 0; i < 8; ++i) {
            if (i & 1) { EDGE(yy[i], accB1) }
            else       { EDGE(yy[i], accB0) }
        }
    }
#undef EDGE
    float a0 = accA0.x + accA1.x, a1 = accA0.y + accA1.y;
    float c0 = accB0.x + accB1.x, c1 = accB0.y + accB1.y;
    if (!FINAL) {
        int pkA = __builtin_amdgcn_cvt_pk_fp8_f32(a0, a1, 0, false);
        int pkB = __builtin_amdgcn_cvt_pk_fp8_f32(c0, c1, 0, false);
        ((unsigned short*)hout)[(size_t)rA * (D / 2) + lane] = (unsigned short)pkA;
        ((unsigned short*)hout)[(size_t)rB * (D / 2) + lane] = (unsigned short)pkB;
    } else {
        // row A
        a0 *= INV_FSCALE; a1 *= INV_FSCALE;
        float sqA = a1 * a1 + (lane == 0 ? 0.0f : a0 * a0);
        #pragma unroll
        for (int off = 1; off < 64; off <<= 1) sqA += __shfl_xor(sqA, off, 64);
        float vnA = fmaxf(sqrtf(sqA), MIN_NORM);
        float shA = sinhf(vnA);
        float scA = shA / vnA;
        float fsA = sqrtf(fmaxf(1.0f + shA * shA, EPS));
        float2 oA;
        oA.x = (lane == 0) ? fsA : a0 * scA;
        oA.y = a1 * scA;
        reinterpret_cast<float2*>((float*)hout + (size_t)rA * D)[lane] = oA;
        // row B
        c0 *= INV_FSCALE; c1 *= INV_FSCALE;
        float sqB = c1 * c1 + (lane == 0 ? 0.0f : c0 * c0);
        #pragma unroll
        for (int off = 1; off < 64; off <<= 1) sqB += __shfl_xor(sqB, off, 64);
        float vnB = fmaxf(sqrtf(sqB), MIN_NORM);
        float shB = sinhf(vnB);
        float scB = shB / vnB;
        float fsB = sqrtf(fmaxf(1.0f + shB * shB, EPS));
        float2 oB;
        oB.x = (lane == 0) ? fsB : c0 * scB;
        oB.y = c1 * scB;
        reinterpret_cast<float2*>((float*)hout + (size_t)rB * D)[lane] = oB;
    }
}

// ---------------------------------------------------------------------------
extern "C" void kernel_launch(void* const* d_in, const int* in_sizes, int n_in,
                              void* d_out, int out_size, void* d_ws, size_t ws_size,
                              hipStream_t stream) {
    const float* x    = (const float*)d_in[0];
    const int*   rows = (const int*)d_in[1];
    const int*   cols = (const int*)d_in[2];
    const float* vals = (const float*)d_in[3];
    float* out = (float*)d_out;
    int E = in_sizes[1];

    // workspace (~32.6 MB): tmp (16 MB, CAP-strided) is live only during the
    // build; hA/hB (6.4 MB each, fp8) alias it afterwards.
    char* ws = (char*)d_ws;
    size_t REG = (size_t)NBUCK * CAP;                      // bucket-region entries
    int2*           tmp  = (int2*)ws;                      // REG * 8 B
    unsigned short* hA   = (unsigned short*)ws;            // N*D/2 ushort (6.4 MB)
    unsigned short* hB   = (unsigned short*)(ws + (size_t)N_NODES * D);
    uint2*    epay    = (uint2*)(ws + REG * 8);            // REG * 8 B
    int2*     rowptr2 = (int2*)(ws + REG * 16);            // N int2 (16B aligned)
    int*      gcur    = (int*)(rowptr2 + N_NODES);         // NBUCK

    int eb = (E + CHUNK - 1) / CHUNK;
    int sb = (N_NODES + 7) / 8;      // 2 rows per wave, 4 waves per block
    int lb = (N_NODES + 3) / 4;      // logmap: 1 row per wave, 4 waves per block

    zerog_kernel<<<1, 256, 0, stream>>>(gcur);
    binA_kernel<<<eb, 256, 0, stream>>>(rows, cols, vals, gcur, tmp, E);
    binB_kernel<<<NBUCK, 256, 0, stream>>>(tmp, gcur, rowptr2, epay);

    // h0 = FSCALE * logmap0(x) -> hA (fp8), overwriting tmp
    logmap0_kernel<<<lb, 256, 0, stream>>>(x, hA);

    // layer 1: hA -> hB ; layer 2: hB -> hA ; layer 3 fused: hA -> out (fp32)
    spmm_kernel<false><<<sb, 256, 0, stream>>>((const int4*)rowptr2, epay, hA, hB);
    spmm_kernel<false><<<sb, 256, 0, stream>>>((const int4*)rowptr2, epay, hB, hA);
    spmm_kernel<true ><<<sb, 256, 0, stream>>>((const int4*)rowptr2, epay, hA, out);
}

// Round 17
// 151.382 us; speedup vs baseline: 1.0772x; 1.0772x over previous
//
#include <hip/hip_runtime.h>
#include <math.h>

#define N_NODES 50000
#define D 128
#define MIN_NORM 1e-15f
#define EPS 1e-5f
#define NBUCK 196        // ceil(N_NODES / 256)
#define CHUNK 4096       // edges per block in binA
#define CAP 10240        // bucket capacity (mean 8163 + 8-pad mean ~900 + margin)
#define FSCALE 32.0f     // fp8 storage pre-scale (cancels through linear SpMM)
#define INV_FSCALE (1.0f / 32.0f)

typedef float fx2 __attribute__((ext_vector_type(2)));

// ---------------------------------------------------------------------------
__global__ void zerog_kernel(int* __restrict__ gcur) {
    if (threadIdx.x < NBUCK) gcur[threadIdx.x] = 0;
}

// ---------------------------------------------------------------------------
// binA: count + scatter into CAP-strided bucket regions of tmp.
// Payload packs (rowlocal<<16)|col in .x, f32 val bits in .y.
// ---------------------------------------------------------------------------
__global__ __launch_bounds__(256) void binA_kernel(const int* __restrict__ rows,
                                                   const int* __restrict__ cols,
                                                   const float* __restrict__ vals,
                                                   int* __restrict__ gcur,
                                                   int2* __restrict__ tmp, int E) {
    __shared__ int lh[NBUCK];
    __shared__ int lb[NBUCK];
    for (int i = threadIdx.x; i < NBUCK; i += 256) lh[i] = 0;
    __syncthreads();
    int start = blockIdx.x * CHUNK;
    int end = min(start + CHUNK, E);
    for (int i = start + threadIdx.x; i < end; i += 256)
        atomicAdd(&lh[rows[i] >> 8], 1);
    __syncthreads();
    for (int i = threadIdx.x; i < NBUCK; i += 256) {
        int c = lh[i];
        lb[i] = i * CAP + (c ? atomicAdd(&gcur[i], c) : 0);
        lh[i] = 0;
    }
    __syncthreads();
    for (int i = start + threadIdx.x; i < end; i += 256) {
        int r = rows[i];
        int b = r >> 8;
        int ofs = atomicAdd(&lh[b], 1);
        tmp[lb[b] + ofs] = make_int2(((r & 255) << 16) | cols[i], __float_as_int(vals[i]));
    }
}

// ---------------------------------------------------------------------------
// binB: one block per bucket. Sort bucket edges by local row via 256-entry
// LDS histogram + scan over counts ROUNDED UP TO MULTIPLES OF 8; emit
// rowptr2 = (startEdge, endEdge=start+rounded) and row-sorted epay
// uint2{ col<<7 (byte offset into h), f32 val bits }. Rows padded to a
// multiple of 8 edges with (col=0, val=0) so the SpMM loop is tail-free.
// ---------------------------------------------------------------------------
__global__ __launch_bounds__(256) void binB_kernel(const int2* __restrict__ tmp,
                                                   const int* __restrict__ gcur,
                                                   int2* __restrict__ rowptr2,
                                                   uint2* __restrict__ epay) {
    __shared__ int hist[256];
    __shared__ int wsum[4];
    int b = blockIdx.x;
    int base = b * CAP;
    int nloc = gcur[b];
    int tid = threadIdx.x;
    hist[tid] = 0;
    __syncthreads();
    for (int i = tid; i < nloc; i += 256)
        atomicAdd(&hist[tmp[base + i].x >> 16], 1);
    __syncthreads();
    int lane = tid & 63, wid = tid >> 6;
    int v = hist[tid];
    int r = (v + 7) & ~7;            // 8-rounded count
    int x = r;
    #pragma unroll
    for (int off = 1; off < 64; off <<= 1) {
        int t = __shfl_up(x, off, 64);
        if (lane >= off) x += t;
    }
    if (lane == 63) wsum[wid] = x;
    __syncthreads();
    if (tid == 0) {
        int s0 = wsum[0], s1 = wsum[1], s2 = wsum[2];
        wsum[0] = 0; wsum[1] = s0; wsum[2] = s0 + s1; wsum[3] = s0 + s1 + s2;
    }
    __syncthreads();
    int excl = x - r + wsum[wid];    // 8-aligned start within bucket
    int g = (b << 8) + tid;
    if (g < N_NODES) rowptr2[g] = make_int2(base + excl, base + excl + r);
    __syncthreads();
    hist[tid] = excl;                // per-row scatter cursor
    __syncthreads();
    for (int i = tid; i < nloc; i += 256) {
        int2 p = tmp[base + i];
        int rl = p.x >> 16;
        unsigned col = (unsigned)(p.x & 0xffff);
        int pos = base + atomicAdd(&hist[rl], 1);
        epay[pos] = make_uint2(col << 7, (unsigned)p.y);
    }
    // pad each row to its 8-rounded length (col 0, val 0)
    for (int k = v; k < r; ++k)
        epay[base + excl + k] = make_uint2(0u, 0u);
}

// ---------------------------------------------------------------------------
// h = FSCALE * logmap0(x) -> fp8 e4m3. 4 waves/block, one wave per row;
// lane owns cols {2l, 2l+1}; packed fp8 pair stored as ushort.
// ---------------------------------------------------------------------------
__global__ __launch_bounds__(256) void logmap0_kernel(const float* __restrict__ x,
                                                      unsigned short* __restrict__ h) {
    int lane = threadIdx.x & 63;
    int row = blockIdx.x * 4 + (threadIdx.x >> 6);
    const float2* xr = reinterpret_cast<const float2*>(x + (size_t)row * D);
    float2 v = xr[lane];
    float x0 = __shfl(v.x, 0, 64);
    float sq = v.y * v.y + (lane == 0 ? 0.0f : v.x * v.x);
    #pragma unroll
    for (int off = 1; off < 64; off <<= 1) sq += __shfl_xor(sq, off, 64);
    float ynorm = fmaxf(sqrtf(sq), MIN_NORM);
    float theta = fmaxf(x0, 1.0f + EPS);
    float scale = FSCALE * acoshf(theta) / ynorm;
    float ox = (lane == 0) ? 0.0f : v.x * scale;
    float oy = v.y * scale;
    int packed = __builtin_amdgcn_cvt_pk_fp8_f32(ox, oy, 0, false);
    h[(size_t)row * (D / 2) + lane] = (unsigned short)packed;
}

// ---------------------------------------------------------------------------
// Scalar-pipe CSR SpMM, TWO rows per wave, tail-free (rows 8-padded).
// Edge payloads are wave-uniform -> s_load batches; per edge the VALU does
// {ushort gather, cvt_pk_f32_fp8, v_pk_fma_f32} = 2 VALU + 1 VMEM.
// Lane owns cols {2l, 2l+1} (fx2 accumulator -> packed FMA).
// MID: store fp8 (keeps FSCALE). FINAL: fused out = proj(expmap0(acc/FSCALE)).
// ---------------------------------------------------------------------------
template <bool FINAL>
__global__ __launch_bounds__(256) void spmm_kernel(const int4* __restrict__ rowptr4,
                                                   const uint2* __restrict__ epay,
                                                   const unsigned short* __restrict__ hin,
                                                   void* __restrict__ hout) {
    int lane = threadIdx.x & 63;
    int pr = __builtin_amdgcn_readfirstlane(blockIdx.x * 4 + (threadIdx.x >> 6));
    int rA = pr * 2, rB = pr * 2 + 1;
    int4 rp = rowptr4[pr];                     // (startA, endA, startB, endB)
    int ja = __builtin_amdgcn_readfirstlane(rp.x), ea = __builtin_amdgcn_readfirstlane(rp.y);
    int jb = __builtin_amdgcn_readfirstlane(rp.z), eb = __builtin_amdgcn_readfirstlane(rp.w);
    const char* hb = (const char*)hin;
    int lo = lane << 1;
    fx2 accA0 = {0.f, 0.f}, accA1 = {0.f, 0.f};   // row A (2 sub-chains)
    fx2 accB0 = {0.f, 0.f}, accB1 = {0.f, 0.f};   // row B (2 sub-chains)
#define EDGE(E, ACC) {                                                        \
    unsigned short g8 = *(const unsigned short*)(hb + (E).x + lo);            \
    fx2 f = __builtin_amdgcn_cvt_pk_f32_fp8((int)g8, false);                  \
    float vs = __uint_as_float((E).y);                                        \
    fx2 vv = {vs, vs};                                                        \
    ACC += f * vv; }
    while (ja < ea && jb < eb) {
        uint2 x0 = epay[ja],     x1 = epay[ja + 1], x2 = epay[ja + 2], x3 = epay[ja + 3];
        uint2 x4 = epay[ja + 4], x5 = epay[ja + 5], x6 = epay[ja + 6], x7 = epay[ja + 7];
        uint2 y0 = epay[jb],     y1 = epay[jb + 1], y2 = epay[jb + 2], y3 = epay[jb + 3];
        uint2 y4 = epay[jb + 4], y5 = epay[jb + 5], y6 = epay[jb + 6], y7 = epay[jb + 7];
        EDGE(x0, accA0) EDGE(y0, accB0) EDGE(x1, accA1) EDGE(y1, accB1)
        EDGE(x2, accA0) EDGE(y2, accB0) EDGE(x3, accA1) EDGE(y3, accB1)
        EDGE(x4, accA0) EDGE(y4, accB0) EDGE(x5, accA1) EDGE(y5, accB1)
        EDGE(x6, accA0) EDGE(y6, accB0) EDGE(x7, accA1) EDGE(y7, accB1)
        ja += 8; jb += 8;
    }
    for (; ja < ea; ja += 8) {
        uint2 x0 = epay[ja],     x1 = epay[ja + 1], x2 = epay[ja + 2], x3 = epay[ja + 3];
        uint2 x4 = epay[ja + 4], x5 = epay[ja + 5], x6 = epay[ja + 6], x7 = epay[ja + 7];
        EDGE(x0, accA0) EDGE(x1, accA1) EDGE(x2, accA0) EDGE(x3, accA1)
        EDGE(x4, accA0) EDGE(x5, accA1) EDGE(x6, accA0) EDGE(x7, accA1)
    }
    for (; jb < eb; jb += 8) {
        uint2 y0 = epay[jb],     y1 = epay[jb + 1], y2 = epay[jb + 2], y3 = epay[jb + 3];
        uint2 y4 = epay[jb + 4], y5 = epay[jb + 5], y6 = epay[jb + 6], y7 = epay[jb + 7];
        EDGE(y0, accB0) EDGE(y1, accB1) EDGE(y2, accB0) EDGE(y3, accB1)
        EDGE(y4, accB0) EDGE(y5, accB1) EDGE(y6, accB0) EDGE(y7, accB1)
    }
#undef EDGE
    float a0 = accA0.x + accA1.x, a1 = accA0.y + accA1.y;
    float c0 = accB0.x + accB1.x, c1 = accB0.y + accB1.y;
    if (!FINAL) {
        int pkA = __builtin_amdgcn_cvt_pk_fp8_f32(a0, a1, 0, false);
        int pkB = __builtin_amdgcn_cvt_pk_fp8_f32(c0, c1, 0, false);
        ((unsigned short*)hout)[(size_t)rA * (D / 2) + lane] = (unsigned short)pkA;
        ((unsigned short*)hout)[(size_t)rB * (D / 2) + lane] = (unsigned short)pkB;
    } else {
        // row A
        a0 *= INV_FSCALE; a1 *= INV_FSCALE;
        float sqA = a1 * a1 + (lane == 0 ? 0.0f : a0 * a0);
        #pragma unroll
        for (int off = 1; off < 64; off <<= 1) sqA += __shfl_xor(sqA, off, 64);
        float vnA = fmaxf(sqrtf(sqA), MIN_NORM);
        float shA = sinhf(vnA);
        float scA = shA / vnA;
        float fsA = sqrtf(fmaxf(1.0f + shA * shA, EPS));
        float2 oA;
        oA.x = (lane == 0) ? fsA : a0 * scA;
        oA.y = a1 * scA;
        reinterpret_cast<float2*>((float*)hout + (size_t)rA * D)[lane] = oA;
        // row B
        c0 *= INV_FSCALE; c1 *= INV_FSCALE;
        float sqB = c1 * c1 + (lane == 0 ? 0.0f : c0 * c0);
        #pragma unroll
        for (int off = 1; off < 64; off <<= 1) sqB += __shfl_xor(sqB, off, 64);
        float vnB = fmaxf(sqrtf(sqB), MIN_NORM);
        float shB = sinhf(vnB);
        float scB = shB / vnB;
        float fsB = sqrtf(fmaxf(1.0f + shB * shB, EPS));
        float2 oB;
        oB.x = (lane == 0) ? fsB : c0 * scB;
        oB.y = c1 * scB;
        reinterpret_cast<float2*>((float*)hout + (size_t)rB * D)[lane] = oB;
    }
}

// ---------------------------------------------------------------------------
extern "C" void kernel_launch(void* const* d_in, const int* in_sizes, int n_in,
                              void* d_out, int out_size, void* d_ws, size_t ws_size,
                              hipStream_t stream) {
    const float* x    = (const float*)d_in[0];
    const int*   rows = (const int*)d_in[1];
    const int*   cols = (const int*)d_in[2];
    const float* vals = (const float*)d_in[3];
    float* out = (float*)d_out;
    int E = in_sizes[1];

    // workspace (~32.6 MB): tmp (16 MB, CAP-strided) is live only during the
    // build; hA/hB (6.4 MB each, fp8) alias it afterwards.
    char* ws = (char*)d_ws;
    size_t REG = (size_t)NBUCK * CAP;                      // bucket-region entries
    int2*           tmp  = (int2*)ws;                      // REG * 8 B
    unsigned short* hA   = (unsigned short*)ws;            // N*D/2 ushort (6.4 MB)
    unsigned short* hB   = (unsigned short*)(ws + (size_t)N_NODES * D);
    uint2*    epay    = (uint2*)(ws + REG * 8);            // REG * 8 B
    int2*     rowptr2 = (int2*)(ws + REG * 16);            // N int2 (16B aligned)
    int*      gcur    = (int*)(rowptr2 + N_NODES);         // NBUCK

    int eb = (E + CHUNK - 1) / CHUNK;
    int sb = (N_NODES + 7) / 8;      // 2 rows per wave, 4 waves per block
    int lb = (N_NODES + 3) / 4;      // logmap: 1 row per wave, 4 waves per block

    zerog_kernel<<<1, 256, 0, stream>>>(gcur);
    binA_kernel<<<eb, 256, 0, stream>>>(rows, cols, vals, gcur, tmp, E);
    binB_kernel<<<NBUCK, 256, 0, stream>>>(tmp, gcur, rowptr2, epay);

    // h0 = FSCALE * logmap0(x) -> hA (fp8), overwriting tmp
    logmap0_kernel<<<lb, 256, 0, stream>>>(x, hA);

    // layer 1: hA -> hB ; layer 2: hB -> hA ; layer 3 fused: hA -> out (fp32)
    spmm_kernel<false><<<sb, 256, 0, stream>>>((const int4*)rowptr2, epay, hA, hB);
    spmm_kernel<false><<<sb, 256, 0, stream>>>((const int4*)rowptr2, epay, hB, hA);
    spmm_kernel<true ><<<sb, 256, 0, stream>>>((const int4*)rowptr2, epay, hA, out);
}